// Round 1
// baseline (1343.102 us; speedup 1.0000x reference)
//
#include <hip/hip_runtime.h>
#include <hip/hip_bf16.h>
#include <math.h>

#define BB 4
#define SS 2048
#define EE 1024
#define HH 8
#define DD 128
#define BSR (BB*SS)      // 8192 rows
#define HD  (HH*DD)      // 1024
#define LNEPS 1e-5f

// ---------------------------------------------------------------- prep -----
// q[h,d] = sum_e W2[h,d,e]*w_att[e];  c[h] = sum_e b2[h,e]*w_att[e] + b_att
// plus the three diagonals uh_d/uz_d/os_d [H*D]
__global__ __launch_bounds__(256)
void prep_k(const float* __restrict__ W2, const float* __restrict__ w_att,
            const float* __restrict__ b2, const float* __restrict__ b_att,
            const float* __restrict__ Uh, const float* __restrict__ Uz,
            const float* __restrict__ Os,
            float* __restrict__ q, float* __restrict__ c,
            float* __restrict__ uh_d, float* __restrict__ uz_d,
            float* __restrict__ os_d)
{
    const int gid  = blockIdx.x * 256 + threadIdx.x;
    const int wave = gid >> 6, lane = gid & 63;
    if (wave < HD) {
        const float* wp = W2 + (size_t)wave * EE;
        float p = 0.f;
        for (int e = lane; e < EE; e += 64) p = fmaf(wp[e], w_att[e], p);
        #pragma unroll
        for (int off = 32; off > 0; off >>= 1) p += __shfl_xor(p, off, 64);
        if (lane == 0) {
            q[wave] = p;
            const int h = wave >> 7, d = wave & 127;
            uh_d[wave] = Uh[(size_t)h*DD*DD + (size_t)d*DD + d];
            uz_d[wave] = Uz[(size_t)h*DD*DD + (size_t)d*DD + d];
            os_d[wave] = Os[(size_t)h*DD*DD + (size_t)d*DD + d];
        }
    } else if (wave < HD + HH) {
        const int h = wave - HD;
        const float* bp = b2 + (size_t)h * EE;
        float p = 0.f;
        for (int e = lane; e < EE; e += 64) p = fmaf(bp[e], w_att[e], p);
        #pragma unroll
        for (int off = 32; off > 0; off >>= 1) p += __shfl_xor(p, off, 64);
        if (lane == 0) c[h] = p + b_att[0];
    }
}

// ---------------------------------------------------------------- GEMM -----
// C[r,c] = epi( sum_k A[r,k]*B[k,c] ).  128x128 tile, BK=8, 256 thr, 8x8 micro.
// EPI 0: tanh(v + bias[c])          (z = tanh(x@W_ez + b_ez))
// EPI 1: gelu(v + bias[c]) exact    (h1, per-head via blockIdx.z)
// EPI 2: v + sum_h scores[r,h]*b2[h,c]   (weighted)
template<int EPI>
__global__ __launch_bounds__(256)
void gemm_k(const float* __restrict__ A, int lda, int aOff,
            const float* __restrict__ Bm, int ldb, int bOff,
            float* __restrict__ C, int ldc, int cOff,
            int K,
            const float* __restrict__ bias, int biasOff,
            const float* __restrict__ scores,
            const float* __restrict__ b2)
{
    const int zb = blockIdx.z;
    const float* Ab = A  + (size_t)zb * aOff;
    const float* Bb = Bm + (size_t)zb * bOff;
    float*       Cb = C  + (size_t)zb * cOff;
    const float* biasb = bias + (size_t)zb * biasOff;
    const int row0 = blockIdx.x * 128;
    const int col0 = blockIdx.y * 128;

    __shared__ float Asm[8][128];
    __shared__ float Bsm[8][128];

    const int t  = threadIdx.x;
    const int tx = t & 15, ty = t >> 4;
    const int am = t >> 1, ak = (t & 1) * 4;
    const int bk = t >> 5, bn = (t & 31) * 4;

    float acc[8][8];
    #pragma unroll
    for (int i = 0; i < 8; ++i)
        #pragma unroll
        for (int j = 0; j < 8; ++j) acc[i][j] = 0.f;

    for (int k0 = 0; k0 < K; k0 += 8) {
        const float4 av = *(const float4*)(Ab + (size_t)(row0 + am) * lda + k0 + ak);
        const float4 bv = *(const float4*)(Bb + (size_t)(k0 + bk) * ldb + col0 + bn);
        __syncthreads();
        Asm[ak+0][am] = av.x; Asm[ak+1][am] = av.y;
        Asm[ak+2][am] = av.z; Asm[ak+3][am] = av.w;
        *(float4*)&Bsm[bk][bn] = bv;
        __syncthreads();
        #pragma unroll
        for (int kk = 0; kk < 8; ++kk) {
            float a[8], b[8];
            *(float4*)&a[0] = *(const float4*)&Asm[kk][ty*8];
            *(float4*)&a[4] = *(const float4*)&Asm[kk][ty*8+4];
            *(float4*)&b[0] = *(const float4*)&Bsm[kk][tx*8];
            *(float4*)&b[4] = *(const float4*)&Bsm[kk][tx*8+4];
            #pragma unroll
            for (int i = 0; i < 8; ++i)
                #pragma unroll
                for (int j = 0; j < 8; ++j)
                    acc[i][j] = fmaf(a[i], b[j], acc[i][j]);
        }
    }

    #pragma unroll
    for (int i = 0; i < 8; ++i) {
        const int r = row0 + ty*8 + i;
        float sc[HH];
        if (EPI == 2) {
            #pragma unroll
            for (int h = 0; h < HH; ++h) sc[h] = scores[r*HH + h];
        }
        float outv[8];
        #pragma unroll
        for (int j = 0; j < 8; ++j) {
            const int cidx = col0 + tx*8 + j;
            float v = acc[i][j];
            if (EPI == 0) {
                v = tanhf(v + biasb[cidx]);
            } else if (EPI == 1) {
                v += biasb[cidx];
                v = 0.5f * v * (1.f + erff(v * 0.70710678118654752f));
            } else {
                float bb = 0.f;
                #pragma unroll
                for (int h = 0; h < HH; ++h) bb = fmaf(sc[h], b2[(size_t)h*EE + cidx], bb);
                v += bb;
            }
            outv[j] = v;
        }
        *(float4*)(Cb + (size_t)r*ldc + col0 + tx*8)     = *(float4*)&outv[0];
        *(float4*)(Cb + (size_t)r*ldc + col0 + tx*8 + 4) = *(float4*)&outv[4];
    }
}

// ---------------------------------------------------------------- scan -----
// one wave per (b,h); lane holds d and d+64; 2048 sequential steps with
// chunk-8 register prefetch of z to hide load latency.
__global__ __launch_bounds__(64)
void scan_k(const float* __restrict__ z,
            const float* __restrict__ uh_d, const float* __restrict__ uz_d,
            const float* __restrict__ b_u,
            const float* __restrict__ lns_g, const float* __restrict__ lns_b,
            float* __restrict__ states)
{
    const int bh = blockIdx.x;            // b*H + h
    const int b = bh >> 3, h = bh & 7;
    const int lane = threadIdx.x;
    const int d0 = lane, d1 = lane + 64;

    const float uh0 = uh_d[h*DD + d0], uh1 = uh_d[h*DD + d1];
    const float uz0 = uz_d[h*DD + d0], uz1 = uz_d[h*DD + d1];
    const float bu0 = b_u [h*DD + d0], bu1 = b_u [h*DD + d1];
    const float g0  = lns_g[d0], g1 = lns_g[d1];
    const float be0 = lns_b[d0], be1 = lns_b[d1];

    const float* zp = z      + ((size_t)b * SS * HH + h) * DD;
    float*       sp = states + ((size_t)b * SS * HH + h) * DD;

    float hp0 = 0.f, hp1 = 0.f;
    const int CH = 8;
    float zc0[CH], zc1[CH];
    #pragma unroll
    for (int i = 0; i < CH; ++i) {
        zc0[i] = zp[(size_t)i*HD + d0];
        zc1[i] = zp[(size_t)i*HD + d1];
    }

    for (int s0 = 0; s0 < SS; s0 += CH) {
        float zn0[CH], zn1[CH];
        if (s0 + CH < SS) {
            #pragma unroll
            for (int i = 0; i < CH; ++i) {
                zn0[i] = zp[(size_t)(s0+CH+i)*HD + d0];
                zn1[i] = zp[(size_t)(s0+CH+i)*HD + d1];
            }
        } else {
            #pragma unroll
            for (int i = 0; i < CH; ++i) { zn0[i] = 0.f; zn1[i] = 0.f; }
        }
        #pragma unroll
        for (int i = 0; i < CH; ++i) {
            const float z0 = zc0[i], z1 = zc1[i];
            const float t0 = fmaf(hp0, uh0, fmaf(z0, uz0, bu0));
            const float t1 = fmaf(hp1, uh1, fmaf(z1, uz1, bu1));
            const float u0 = 1.f / (1.f + __expf(-t0));
            const float u1 = 1.f / (1.f + __expf(-t1));
            const float hn0 = fmaf(u0, hp0 - z0, z0);
            const float hn1 = fmaf(u1, hp1 - z1, z1);
            float s1 = hn0 + hn1;
            float s2 = fmaf(hn0, hn0, hn1*hn1);
            #pragma unroll
            for (int off = 32; off > 0; off >>= 1) {
                s1 += __shfl_xor(s1, off, 64);
                s2 += __shfl_xor(s2, off, 64);
            }
            const float m   = s1 * (1.f/128.f);
            const float var = fmaf(s2, 1.f/128.f, -m*m);
            const float r   = rsqrtf(var + LNEPS);
            hp0 = fmaf((hn0 - m) * r, g0, be0);
            hp1 = fmaf((hn1 - m) * r, g1, be1);
            sp[(size_t)(s0+i)*HD + d0] = hp0;
            sp[(size_t)(s0+i)*HD + d1] = hp1;
        }
        #pragma unroll
        for (int i = 0; i < CH; ++i) { zc0[i] = zn0[i]; zc1[i] = zn1[i]; }
    }
}

// ------------------------------------------------- per-head diag+LN --------
__global__ __launch_bounds__(256)
void headln_k(const float* __restrict__ states, const float* __restrict__ os_d,
              const float* __restrict__ ffg, const float* __restrict__ ffb,
              float* __restrict__ hln)
{
    const int gid  = blockIdx.x * 256 + threadIdx.x;
    const int row  = gid >> 6;            // bs*H + h  (< 65536)
    const int lane = gid & 63;
    const int h = row & 7;
    const float* xp = states + (size_t)row * DD;
    const float x0 = xp[lane]      * os_d[h*DD + lane];
    const float x1 = xp[lane + 64] * os_d[h*DD + lane + 64];
    float s1 = x0 + x1;
    float s2 = fmaf(x0, x0, x1*x1);
    #pragma unroll
    for (int off = 32; off > 0; off >>= 1) {
        s1 += __shfl_xor(s1, off, 64);
        s2 += __shfl_xor(s2, off, 64);
    }
    const float m   = s1 * (1.f/128.f);
    const float var = fmaf(s2, 1.f/128.f, -m*m);
    const float r   = rsqrtf(var + LNEPS);
    float* op = hln + (size_t)row * DD;
    op[lane]      = fmaf((x0 - m)*r, ffg[h*DD + lane],      ffb[h*DD + lane]);
    op[lane + 64] = fmaf((x1 - m)*r, ffg[h*DD + lane + 64], ffb[h*DD + lane + 64]);
}

// ---------------------------------------------------------------- logits ---
__global__ __launch_bounds__(256)
void logits_k(const float* __restrict__ h1, const float* __restrict__ q,
              const float* __restrict__ c, float* __restrict__ logits)
{
    const int gid  = blockIdx.x * 256 + threadIdx.x;
    const int row  = gid >> 6;            // bs*H + h
    const int lane = gid & 63;
    const int h = row & 7;
    const float* xp = h1 + (size_t)row * DD;
    float p = fmaf(xp[lane], q[h*DD + lane], xp[lane+64] * q[h*DD + lane + 64]);
    #pragma unroll
    for (int off = 32; off > 0; off >>= 1) p += __shfl_xor(p, off, 64);
    if (lane == 0) logits[row] = p + c[h];
}

// --------------------------------------------- softmax + scale h1 → g ------
__global__ __launch_bounds__(256)
void softscale_k(const float* __restrict__ h1, const float* __restrict__ logits,
                 float* __restrict__ g, float* __restrict__ scores)
{
    const int gid = blockIdx.x * 256 + threadIdx.x;   // 2M threads, float4 each
    const size_t idx = (size_t)gid * 4;
    const int bs = (int)(idx >> 10);
    const int h  = (int)((idx >> 7) & 7);
    float l[8];
    float mx = -1e30f;
    #pragma unroll
    for (int i = 0; i < 8; ++i) { l[i] = logits[bs*8 + i]; mx = fmaxf(mx, l[i]); }
    float den = 0.f;
    #pragma unroll
    for (int i = 0; i < 8; ++i) den += __expf(l[i] - mx);
    const float sc = __expf(l[h] - mx) / den;
    float4 v = *(const float4*)(h1 + idx);
    v.x *= sc; v.y *= sc; v.z *= sc; v.w *= sc;
    *(float4*)(g + idx) = v;
    if ((idx & 127) == 0) scores[bs*8 + h] = sc;
}

// ---------------------------------------------------------------- final LN -
__global__ __launch_bounds__(256)
void finalln_k(const float* __restrict__ w, const float* __restrict__ g,
               const float* __restrict__ b, float* __restrict__ out)
{
    const int row = blockIdx.x;
    const int t = threadIdx.x;
    const float* xp = w + (size_t)row * EE;
    const float4 v = *(const float4*)(xp + t*4);
    float s1 = v.x + v.y + v.z + v.w;
    float s2 = v.x*v.x + v.y*v.y + v.z*v.z + v.w*v.w;
    #pragma unroll
    for (int off = 32; off > 0; off >>= 1) {
        s1 += __shfl_xor(s1, off, 64);
        s2 += __shfl_xor(s2, off, 64);
    }
    __shared__ float r1[4], r2[4];
    if ((t & 63) == 0) { r1[t>>6] = s1; r2[t>>6] = s2; }
    __syncthreads();
    s1 = r1[0] + r1[1] + r1[2] + r1[3];
    s2 = r2[0] + r2[1] + r2[2] + r2[3];
    const float m   = s1 * (1.f/1024.f);
    const float var = fmaf(s2, 1.f/1024.f, -m*m);
    const float r   = rsqrtf(var + LNEPS);
    const float4 gv = *(const float4*)(g + t*4);
    const float4 bv = *(const float4*)(b + t*4);
    float4 o;
    o.x = fmaf((v.x - m)*r, gv.x, bv.x);
    o.y = fmaf((v.y - m)*r, gv.y, bv.y);
    o.z = fmaf((v.z - m)*r, gv.z, bv.z);
    o.w = fmaf((v.w - m)*r, gv.w, bv.w);
    *(float4*)(out + (size_t)row*EE + t*4) = o;
}

// ---------------------------------------------------------------------------
extern "C" void kernel_launch(void* const* d_in, const int* in_sizes, int n_in,
                              void* d_out, int out_size, void* d_ws, size_t ws_size,
                              hipStream_t stream)
{
    const float* x       = (const float*)d_in[0];
    const float* W_ez    = (const float*)d_in[1];
    const float* b_ez    = (const float*)d_in[2];
    const float* U_h     = (const float*)d_in[3];
    const float* U_z     = (const float*)d_in[4];
    const float* b_u     = (const float*)d_in[5];
    const float* outsh   = (const float*)d_in[6];
    const float* lns_g   = (const float*)d_in[7];
    const float* lns_b   = (const float*)d_in[8];
    const float* ff_ln_g = (const float*)d_in[9];
    const float* ff_ln_b = (const float*)d_in[10];
    const float* ff_W1   = (const float*)d_in[11];
    const float* ff_b1   = (const float*)d_in[12];
    const float* ff_W2   = (const float*)d_in[13];
    const float* ff_b2   = (const float*)d_in[14];
    const float* w_att   = (const float*)d_in[15];
    const float* b_att   = (const float*)d_in[16];
    const float* lno_g   = (const float*)d_in[17];
    const float* lno_b   = (const float*)d_in[18];
    float* out = (float*)d_out;

    float* ws = (float*)d_ws;
    const size_t NBIG = (size_t)BSR * HD;      // 8M floats
    float* buf0   = ws;                        // z -> hln -> weighted
    float* buf1   = ws + NBIG;                 // states -> g
    float* buf2   = ws + 2*NBIG;               // h1
    float* logits = ws + 3*NBIG;               // 65536
    float* scores = logits + BSR*HH;           // 65536
    float* qv     = scores + BSR*HH;           // 1024
    float* cv     = qv + HD;                   // 8
    float* uh_d   = cv + 8;                    // 1024
    float* uz_d   = uh_d + HD;                 // 1024
    float* os_d   = uz_d + HD;                 // 1024

    // 0: prep (q, c, diagonals)
    prep_k<<<258, 256, 0, stream>>>(ff_W2, w_att, ff_b2, b_att,
                                    U_h, U_z, outsh, qv, cv, uh_d, uz_d, os_d);
    // 1: z = tanh(x @ W_ez + b_ez)
    gemm_k<0><<<dim3(64, 8, 1), 256, 0, stream>>>(
        x, EE, 0, W_ez, HD, 0, buf0, HD, 0, EE, b_ez, 0, nullptr, nullptr);
    // 2: sequential scan -> states
    scan_k<<<BB*HH, 64, 0, stream>>>(buf0, uh_d, uz_d, b_u, lns_g, lns_b, buf1);
    // 3: diag-scale + per-head LN -> hln (reuse buf0)
    headln_k<<<(BSR*HH*64)/256, 256, 0, stream>>>(buf1, os_d, ff_ln_g, ff_ln_b, buf0);
    // 4: h1 = gelu(hln @ W1[h] + b1[h])  (per-head, blockIdx.z)
    gemm_k<1><<<dim3(64, 1, 8), 256, 0, stream>>>(
        buf0, HD, DD, ff_W1, DD, DD*DD, buf2, HD, DD, DD, ff_b1, DD, nullptr, nullptr);
    // 5: logits = h1 . q[h] + c[h]
    logits_k<<<(BSR*HH*64)/256, 256, 0, stream>>>(buf2, qv, cv, logits);
    // 6: softmax over heads, g = score * h1 (reuse buf1), stash scores
    softscale_k<<<(BSR*HD/4)/256, 256, 0, stream>>>(buf2, logits, buf1, scores);
    // 7: weighted = g @ W2v + sum_h score_h*b2[h,:]  (reuse buf0)
    gemm_k<2><<<dim3(64, 8, 1), 256, 0, stream>>>(
        buf1, HD, 0, ff_W2, EE, 0, buf0, EE, 0, HD, nullptr, 0, scores, ff_b2);
    // 8: final LayerNorm over E -> out
    finalln_k<<<BSR, 256, 0, stream>>>(buf0, lno_g, lno_b, out);
}

// Round 2
// 1051.338 us; speedup vs baseline: 1.2775x; 1.2775x over previous
//
#include <hip/hip_runtime.h>
#include <hip/hip_bf16.h>
#include <math.h>

#define BB 4
#define SS 2048
#define EE 1024
#define HH 8
#define DD 128
#define BSR (BB*SS)      // 8192 rows
#define HD  (HH*DD)      // 1024
#define LNEPS 1e-5f
#define LOG2E 1.4426950408889634f

// ---------------------------------------------------------------- prep -----
__global__ __launch_bounds__(256)
void prep_k(const float* __restrict__ W2, const float* __restrict__ w_att,
            const float* __restrict__ b2, const float* __restrict__ b_att,
            const float* __restrict__ Uh, const float* __restrict__ Uz,
            const float* __restrict__ Os,
            float* __restrict__ q, float* __restrict__ c,
            float* __restrict__ uh_d, float* __restrict__ uz_d,
            float* __restrict__ os_d)
{
    const int gid  = blockIdx.x * 256 + threadIdx.x;
    const int wave = gid >> 6, lane = gid & 63;
    if (wave < HD) {
        const float* wp = W2 + (size_t)wave * EE;
        float p = 0.f;
        for (int e = lane; e < EE; e += 64) p = fmaf(wp[e], w_att[e], p);
        #pragma unroll
        for (int off = 32; off > 0; off >>= 1) p += __shfl_xor(p, off, 64);
        if (lane == 0) {
            q[wave] = p;
            const int h = wave >> 7, d = wave & 127;
            uh_d[wave] = Uh[(size_t)h*DD*DD + (size_t)d*DD + d];
            uz_d[wave] = Uz[(size_t)h*DD*DD + (size_t)d*DD + d];
            os_d[wave] = Os[(size_t)h*DD*DD + (size_t)d*DD + d];
        }
    } else if (wave < HD + HH) {
        const int h = wave - HD;
        const float* bp = b2 + (size_t)h * EE;
        float p = 0.f;
        for (int e = lane; e < EE; e += 64) p = fmaf(bp[e], w_att[e], p);
        #pragma unroll
        for (int off = 32; off > 0; off >>= 1) p += __shfl_xor(p, off, 64);
        if (lane == 0) c[h] = p + b_att[0];
    }
}

// ---------------------------------------------------------------- GEMM -----
// C[r,c] = epi( sum_k A[r,k]*B[k,c] ).  128x128 tile, BK=8, 256 thr, 8x8 micro.
template<int EPI>
__global__ __launch_bounds__(256)
void gemm_k(const float* __restrict__ A, int lda, int aOff,
            const float* __restrict__ Bm, int ldb, int bOff,
            float* __restrict__ C, int ldc, int cOff,
            int K,
            const float* __restrict__ bias, int biasOff,
            const float* __restrict__ scores,
            const float* __restrict__ b2)
{
    const int zb = blockIdx.z;
    const float* Ab = A  + (size_t)zb * aOff;
    const float* Bb = Bm + (size_t)zb * bOff;
    float*       Cb = C  + (size_t)zb * cOff;
    const float* biasb = bias + (size_t)zb * biasOff;
    const int row0 = blockIdx.x * 128;
    const int col0 = blockIdx.y * 128;

    __shared__ float Asm[8][128];
    __shared__ float Bsm[8][128];

    const int t  = threadIdx.x;
    const int tx = t & 15, ty = t >> 4;
    const int am = t >> 1, ak = (t & 1) * 4;
    const int bk = t >> 5, bn = (t & 31) * 4;

    float acc[8][8];
    #pragma unroll
    for (int i = 0; i < 8; ++i)
        #pragma unroll
        for (int j = 0; j < 8; ++j) acc[i][j] = 0.f;

    for (int k0 = 0; k0 < K; k0 += 8) {
        const float4 av = *(const float4*)(Ab + (size_t)(row0 + am) * lda + k0 + ak);
        const float4 bv = *(const float4*)(Bb + (size_t)(k0 + bk) * ldb + col0 + bn);
        __syncthreads();
        Asm[ak+0][am] = av.x; Asm[ak+1][am] = av.y;
        Asm[ak+2][am] = av.z; Asm[ak+3][am] = av.w;
        *(float4*)&Bsm[bk][bn] = bv;
        __syncthreads();
        #pragma unroll
        for (int kk = 0; kk < 8; ++kk) {
            float a[8], b[8];
            *(float4*)&a[0] = *(const float4*)&Asm[kk][ty*8];
            *(float4*)&a[4] = *(const float4*)&Asm[kk][ty*8+4];
            *(float4*)&b[0] = *(const float4*)&Bsm[kk][tx*8];
            *(float4*)&b[4] = *(const float4*)&Bsm[kk][tx*8+4];
            #pragma unroll
            for (int i = 0; i < 8; ++i)
                #pragma unroll
                for (int j = 0; j < 8; ++j)
                    acc[i][j] = fmaf(a[i], b[j], acc[i][j]);
        }
    }

    #pragma unroll
    for (int i = 0; i < 8; ++i) {
        const int r = row0 + ty*8 + i;
        float sc[HH];
        if (EPI == 2) {
            #pragma unroll
            for (int h = 0; h < HH; ++h) sc[h] = scores[r*HH + h];
        }
        float outv[8];
        #pragma unroll
        for (int j = 0; j < 8; ++j) {
            const int cidx = col0 + tx*8 + j;
            float v = acc[i][j];
            if (EPI == 0) {
                v = tanhf(v + biasb[cidx]);
            } else if (EPI == 1) {
                v += biasb[cidx];
                v = 0.5f * v * (1.f + erff(v * 0.70710678118654752f));
            } else {
                float bb = 0.f;
                #pragma unroll
                for (int h = 0; h < HH; ++h) bb = fmaf(sc[h], b2[(size_t)h*EE + cidx], bb);
                v += bb;
            }
            outv[j] = v;
        }
        *(float4*)(Cb + (size_t)r*ldc + col0 + tx*8)     = *(float4*)&outv[0];
        *(float4*)(Cb + (size_t)r*ldc + col0 + tx*8 + 4) = *(float4*)&outv[4];
    }
}

// ------------------------------------------------- DPP wave reduction ------
// v_add_f32 + DPP shift-reduce: lane 63 ends with the 64-lane sum; broadcast
// uniformly via v_readlane. All VALU-latency (no LDS ds_swizzle round-trips).
__device__ __forceinline__ float dpp_add(float x, const int ctrl) {
    // old=0 and bound_ctrl=true both make out-of-row source lanes contribute 0
    int y;
    switch (ctrl) {  // ctrl must be a literal constant for the builtin
        case 0x111: y = __builtin_amdgcn_update_dpp(0, __float_as_int(x), 0x111, 0xf, 0xf, true); break;
        case 0x112: y = __builtin_amdgcn_update_dpp(0, __float_as_int(x), 0x112, 0xf, 0xf, true); break;
        case 0x114: y = __builtin_amdgcn_update_dpp(0, __float_as_int(x), 0x114, 0xf, 0xf, true); break;
        case 0x118: y = __builtin_amdgcn_update_dpp(0, __float_as_int(x), 0x118, 0xf, 0xf, true); break;
        case 0x142: y = __builtin_amdgcn_update_dpp(0, __float_as_int(x), 0x142, 0xf, 0xf, true); break;
        default:    y = __builtin_amdgcn_update_dpp(0, __float_as_int(x), 0x143, 0xf, 0xf, true); break;
    }
    return x + __int_as_float(y);
}

__device__ __forceinline__ float wave_sum64(float x) {
    x = dpp_add(x, 0x111);   // row_shr:1
    x = dpp_add(x, 0x112);   // row_shr:2
    x = dpp_add(x, 0x114);   // row_shr:4
    x = dpp_add(x, 0x118);   // row_shr:8  -> lane 15 of each row-of-16 has row sum
    x = dpp_add(x, 0x142);   // row_bcast:15 -> lane 31 = rows0+1, lane 63 = rows2+3
    x = dpp_add(x, 0x143);   // row_bcast:31 -> lane 63 = total
    return __int_as_float(__builtin_amdgcn_readlane(__float_as_int(x), 63));
}

// ---------------------------------------------------------------- scan -----
// one wave per (b,h); lane holds d and d+64; 2048 sequential steps.
// sigmoid folded to exp2: u = rcp(1 + exp2(hp*uhn + pren)),
// uhn = -uh*log2e (once), pren = fma(z, -uz*log2e, -bu*log2e) (off critical path).
__global__ __launch_bounds__(64)
void scan_k(const float* __restrict__ z,
            const float* __restrict__ uh_d, const float* __restrict__ uz_d,
            const float* __restrict__ b_u,
            const float* __restrict__ lns_g, const float* __restrict__ lns_b,
            float* __restrict__ states)
{
    const int bh = blockIdx.x;            // b*H + h
    const int b = bh >> 3, h = bh & 7;
    const int lane = threadIdx.x;
    const int d0 = lane, d1 = lane + 64;

    const float uhn0 = -uh_d[h*DD + d0] * LOG2E, uhn1 = -uh_d[h*DD + d1] * LOG2E;
    const float uzn0 = -uz_d[h*DD + d0] * LOG2E, uzn1 = -uz_d[h*DD + d1] * LOG2E;
    const float bun0 = -b_u [h*DD + d0] * LOG2E, bun1 = -b_u [h*DD + d1] * LOG2E;
    const float g0  = lns_g[d0], g1 = lns_g[d1];
    const float be0 = lns_b[d0], be1 = lns_b[d1];

    const float* zp = z      + ((size_t)b * SS * HH + h) * DD;
    float*       sp = states + ((size_t)b * SS * HH + h) * DD;

    float hp0 = 0.f, hp1 = 0.f;
    const int CH = 8;
    float zc0[CH], zc1[CH], pr0[CH], pr1[CH];
    #pragma unroll
    for (int i = 0; i < CH; ++i) {
        zc0[i] = zp[(size_t)i*HD + d0];
        zc1[i] = zp[(size_t)i*HD + d1];
    }
    #pragma unroll
    for (int i = 0; i < CH; ++i) {
        pr0[i] = fmaf(zc0[i], uzn0, bun0);
        pr1[i] = fmaf(zc1[i], uzn1, bun1);
    }

    for (int s0 = 0; s0 < SS; s0 += CH) {
        float zn0[CH], zn1[CH];
        if (s0 + CH < SS) {
            #pragma unroll
            for (int i = 0; i < CH; ++i) {
                zn0[i] = zp[(size_t)(s0+CH+i)*HD + d0];
                zn1[i] = zp[(size_t)(s0+CH+i)*HD + d1];
            }
        } else {
            #pragma unroll
            for (int i = 0; i < CH; ++i) { zn0[i] = 0.f; zn1[i] = 0.f; }
        }
        #pragma unroll
        for (int i = 0; i < CH; ++i) {
            const float z0 = zc0[i], z1 = zc1[i];
            // u = sigmoid(hp*uh + z*uz + bu) = rcp(1 + exp2(hp*uhn + pren))
            const float e0 = exp2f(fmaf(hp0, uhn0, pr0[i]));
            const float e1 = exp2f(fmaf(hp1, uhn1, pr1[i]));
            const float d0v = hp0 - z0;           // overlaps exp chain
            const float d1v = hp1 - z1;
            const float u0 = __builtin_amdgcn_rcpf(1.f + e0);
            const float u1 = __builtin_amdgcn_rcpf(1.f + e1);
            const float hn0 = fmaf(u0, d0v, z0);
            const float hn1 = fmaf(u1, d1v, z1);
            const float s1 = wave_sum64(hn0 + hn1);
            const float s2 = wave_sum64(fmaf(hn0, hn0, hn1*hn1));
            const float m   = s1 * (1.f/128.f);
            const float var = fmaf(s2, 1.f/128.f, -m*m);
            const float r   = rsqrtf(var + LNEPS);
            const float rg0 = r * g0, rg1 = r * g1;
            hp0 = fmaf(hn0 - m, rg0, be0);
            hp1 = fmaf(hn1 - m, rg1, be1);
            sp[(size_t)(s0+i)*HD + d0] = hp0;
            sp[(size_t)(s0+i)*HD + d1] = hp1;
        }
        #pragma unroll
        for (int i = 0; i < CH; ++i) {
            zc0[i] = zn0[i]; zc1[i] = zn1[i];
            pr0[i] = fmaf(zn0[i], uzn0, bun0);
            pr1[i] = fmaf(zn1[i], uzn1, bun1);
        }
    }
}

// ------------------------------------------------- per-head diag+LN --------
__global__ __launch_bounds__(256)
void headln_k(const float* __restrict__ states, const float* __restrict__ os_d,
              const float* __restrict__ ffg, const float* __restrict__ ffb,
              float* __restrict__ hln)
{
    const int gid  = blockIdx.x * 256 + threadIdx.x;
    const int row  = gid >> 6;            // bs*H + h  (< 65536)
    const int lane = gid & 63;
    const int h = row & 7;
    const float* xp = states + (size_t)row * DD;
    const float x0 = xp[lane]      * os_d[h*DD + lane];
    const float x1 = xp[lane + 64] * os_d[h*DD + lane + 64];
    float s1 = x0 + x1;
    float s2 = fmaf(x0, x0, x1*x1);
    #pragma unroll
    for (int off = 32; off > 0; off >>= 1) {
        s1 += __shfl_xor(s1, off, 64);
        s2 += __shfl_xor(s2, off, 64);
    }
    const float m   = s1 * (1.f/128.f);
    const float var = fmaf(s2, 1.f/128.f, -m*m);
    const float r   = rsqrtf(var + LNEPS);
    float* op = hln + (size_t)row * DD;
    op[lane]      = fmaf((x0 - m)*r, ffg[h*DD + lane],      ffb[h*DD + lane]);
    op[lane + 64] = fmaf((x1 - m)*r, ffg[h*DD + lane + 64], ffb[h*DD + lane + 64]);
}

// ---------------------------------------------------------------- logits ---
__global__ __launch_bounds__(256)
void logits_k(const float* __restrict__ h1, const float* __restrict__ q,
              const float* __restrict__ c, float* __restrict__ logits)
{
    const int gid  = blockIdx.x * 256 + threadIdx.x;
    const int row  = gid >> 6;            // bs*H + h
    const int lane = gid & 63;
    const int h = row & 7;
    const float* xp = h1 + (size_t)row * DD;
    float p = fmaf(xp[lane], q[h*DD + lane], xp[lane+64] * q[h*DD + lane + 64]);
    #pragma unroll
    for (int off = 32; off > 0; off >>= 1) p += __shfl_xor(p, off, 64);
    if (lane == 0) logits[row] = p + c[h];
}

// --------------------------------------------- softmax + scale h1 → g ------
__global__ __launch_bounds__(256)
void softscale_k(const float* __restrict__ h1, const float* __restrict__ logits,
                 float* __restrict__ g, float* __restrict__ scores)
{
    const int gid = blockIdx.x * 256 + threadIdx.x;   // 2M threads, float4 each
    const size_t idx = (size_t)gid * 4;
    const int bs = (int)(idx >> 10);
    const int h  = (int)((idx >> 7) & 7);
    float l[8];
    float mx = -1e30f;
    #pragma unroll
    for (int i = 0; i < 8; ++i) { l[i] = logits[bs*8 + i]; mx = fmaxf(mx, l[i]); }
    float den = 0.f;
    #pragma unroll
    for (int i = 0; i < 8; ++i) den += __expf(l[i] - mx);
    const float sc = __expf(l[h] - mx) / den;
    float4 v = *(const float4*)(h1 + idx);
    v.x *= sc; v.y *= sc; v.z *= sc; v.w *= sc;
    *(float4*)(g + idx) = v;
    if ((idx & 127) == 0) scores[bs*8 + h] = sc;
}

// ---------------------------------------------------------------- final LN -
__global__ __launch_bounds__(256)
void finalln_k(const float* __restrict__ w, const float* __restrict__ g,
               const float* __restrict__ b, float* __restrict__ out)
{
    const int row = blockIdx.x;
    const int t = threadIdx.x;
    const float* xp = w + (size_t)row * EE;
    const float4 v = *(const float4*)(xp + t*4);
    float s1 = v.x + v.y + v.z + v.w;
    float s2 = v.x*v.x + v.y*v.y + v.z*v.z + v.w*v.w;
    #pragma unroll
    for (int off = 32; off > 0; off >>= 1) {
        s1 += __shfl_xor(s1, off, 64);
        s2 += __shfl_xor(s2, off, 64);
    }
    __shared__ float r1[4], r2[4];
    if ((t & 63) == 0) { r1[t>>6] = s1; r2[t>>6] = s2; }
    __syncthreads();
    s1 = r1[0] + r1[1] + r1[2] + r1[3];
    s2 = r2[0] + r2[1] + r2[2] + r2[3];
    const float m   = s1 * (1.f/1024.f);
    const float var = fmaf(s2, 1.f/1024.f, -m*m);
    const float r   = rsqrtf(var + LNEPS);
    const float4 gv = *(const float4*)(g + t*4);
    const float4 bv = *(const float4*)(b + t*4);
    float4 o;
    o.x = fmaf((v.x - m)*r, gv.x, bv.x);
    o.y = fmaf((v.y - m)*r, gv.y, bv.y);
    o.z = fmaf((v.z - m)*r, gv.z, bv.z);
    o.w = fmaf((v.w - m)*r, gv.w, bv.w);
    *(float4*)(out + (size_t)row*EE + t*4) = o;
}

// ---------------------------------------------------------------------------
extern "C" void kernel_launch(void* const* d_in, const int* in_sizes, int n_in,
                              void* d_out, int out_size, void* d_ws, size_t ws_size,
                              hipStream_t stream)
{
    const float* x       = (const float*)d_in[0];
    const float* W_ez    = (const float*)d_in[1];
    const float* b_ez    = (const float*)d_in[2];
    const float* U_h     = (const float*)d_in[3];
    const float* U_z     = (const float*)d_in[4];
    const float* b_u     = (const float*)d_in[5];
    const float* outsh   = (const float*)d_in[6];
    const float* lns_g   = (const float*)d_in[7];
    const float* lns_b   = (const float*)d_in[8];
    const float* ff_ln_g = (const float*)d_in[9];
    const float* ff_ln_b = (const float*)d_in[10];
    const float* ff_W1   = (const float*)d_in[11];
    const float* ff_b1   = (const float*)d_in[12];
    const float* ff_W2   = (const float*)d_in[13];
    const float* ff_b2   = (const float*)d_in[14];
    const float* w_att   = (const float*)d_in[15];
    const float* b_att   = (const float*)d_in[16];
    const float* lno_g   = (const float*)d_in[17];
    const float* lno_b   = (const float*)d_in[18];
    float* out = (float*)d_out;

    float* ws = (float*)d_ws;
    const size_t NBIG = (size_t)BSR * HD;      // 8M floats
    float* buf0   = ws;                        // z -> hln -> weighted
    float* buf1   = ws + NBIG;                 // states -> g
    float* buf2   = ws + 2*NBIG;               // h1
    float* logits = ws + 3*NBIG;               // 65536
    float* scores = logits + BSR*HH;           // 65536
    float* qv     = scores + BSR*HH;           // 1024
    float* cv     = qv + HD;                   // 8
    float* uh_d   = cv + 8;                    // 1024
    float* uz_d   = uh_d + HD;                 // 1024
    float* os_d   = uz_d + HD;                 // 1024

    // 0: prep (q, c, diagonals)
    prep_k<<<258, 256, 0, stream>>>(ff_W2, w_att, ff_b2, b_att,
                                    U_h, U_z, outsh, qv, cv, uh_d, uz_d, os_d);
    // 1: z = tanh(x @ W_ez + b_ez)
    gemm_k<0><<<dim3(64, 8, 1), 256, 0, stream>>>(
        x, EE, 0, W_ez, HD, 0, buf0, HD, 0, EE, b_ez, 0, nullptr, nullptr);
    // 2: sequential scan -> states
    scan_k<<<BB*HH, 64, 0, stream>>>(buf0, uh_d, uz_d, b_u, lns_g, lns_b, buf1);
    // 3: diag-scale + per-head LN -> hln (reuse buf0)
    headln_k<<<(BSR*HH*64)/256, 256, 0, stream>>>(buf1, os_d, ff_ln_g, ff_ln_b, buf0);
    // 4: h1 = gelu(hln @ W1[h] + b1[h])  (per-head, blockIdx.z)
    gemm_k<1><<<dim3(64, 1, 8), 256, 0, stream>>>(
        buf0, HD, DD, ff_W1, DD, DD*DD, buf2, HD, DD, DD, ff_b1, DD, nullptr, nullptr);
    // 5: logits = h1 . q[h] + c[h]
    logits_k<<<(BSR*HH*64)/256, 256, 0, stream>>>(buf2, qv, cv, logits);
    // 6: softmax over heads, g = score * h1 (reuse buf1), stash scores
    softscale_k<<<(BSR*HD/4)/256, 256, 0, stream>>>(buf2, logits, buf1, scores);
    // 7: weighted = g @ W2v + sum_h score_h*b2[h,:]  (reuse buf0)
    gemm_k<2><<<dim3(64, 8, 1), 256, 0, stream>>>(
        buf1, HD, 0, ff_W2, EE, 0, buf0, EE, 0, HD, nullptr, 0, scores, ff_b2);
    // 8: final LayerNorm over E -> out
    finalln_k<<<BSR, 256, 0, stream>>>(buf0, lno_g, lno_b, out);
}

// Round 4
// 648.803 us; speedup vs baseline: 2.0701x; 1.6204x over previous
//
#include <hip/hip_runtime.h>
#include <hip/hip_bf16.h>
#include <math.h>

#define BB 4
#define SS 2048
#define EE 1024
#define HH 8
#define DD 128
#define BSR (BB*SS)      // 8192 rows
#define HD  (HH*DD)      // 1024
#define LNEPS 1e-5f
#define LOG2E 1.4426950408889634f

typedef __attribute__((ext_vector_type(8))) short bf16x8;
typedef __attribute__((ext_vector_type(4))) float f32x4;

__device__ __forceinline__ ushort f2bf(float f) {
    union { float f; unsigned u; } c{f};
    unsigned r = c.u + 0x7fff + ((c.u >> 16) & 1);   // RNE
    return (ushort)(r >> 16);
}
__device__ __forceinline__ float bf2f(ushort b) {
    union { unsigned u; float f; } c{(unsigned)b << 16};
    return c.f;
}

typedef __attribute__((address_space(1))) const unsigned int GUI;
typedef __attribute__((address_space(3))) unsigned int LUI;
__device__ __forceinline__ void gl_lds16(const ushort* g, ushort* l) {
    __builtin_amdgcn_global_load_lds((GUI*)g, (LUI*)l, 16, 0, 0);
}

// ---------------------------------------------------------------- prep -----
__global__ __launch_bounds__(256)
void prep_k(const float* __restrict__ W2, const float* __restrict__ w_att,
            const float* __restrict__ b2, const float* __restrict__ b_att,
            const float* __restrict__ Uh, const float* __restrict__ Uz,
            const float* __restrict__ Os,
            float* __restrict__ q, float* __restrict__ c,
            float* __restrict__ uh_d, float* __restrict__ uz_d,
            float* __restrict__ os_d)
{
    const int gid  = blockIdx.x * 256 + threadIdx.x;
    const int wave = gid >> 6, lane = gid & 63;
    if (wave < HD) {
        const float* wp = W2 + (size_t)wave * EE;
        float p = 0.f;
        for (int e = lane; e < EE; e += 64) p = fmaf(wp[e], w_att[e], p);
        #pragma unroll
        for (int off = 32; off > 0; off >>= 1) p += __shfl_xor(p, off, 64);
        if (lane == 0) {
            q[wave] = p;
            const int h = wave >> 7, d = wave & 127;
            uh_d[wave] = Uh[(size_t)h*DD*DD + (size_t)d*DD + d];
            uz_d[wave] = Uz[(size_t)h*DD*DD + (size_t)d*DD + d];
            os_d[wave] = Os[(size_t)h*DD*DD + (size_t)d*DD + d];
        }
    } else if (wave < HD + HH) {
        const int h = wave - HD;
        const float* bp = b2 + (size_t)h * EE;
        float p = 0.f;
        for (int e = lane; e < EE; e += 64) p = fmaf(bp[e], w_att[e], p);
        #pragma unroll
        for (int off = 32; off > 0; off >>= 1) p += __shfl_xor(p, off, 64);
        if (lane == 0) c[h] = p + b_att[0];
    }
}

// --------------------------------------- fp32 -> bf16 hi/lo split convert --
__global__ __launch_bounds__(256)
void convx2_k(const float* __restrict__ x,
              ushort* __restrict__ hi, ushort* __restrict__ lo)
{
    const size_t idx = ((size_t)blockIdx.x * 256 + threadIdx.x) * 4;
    const float4 v = *(const float4*)(x + idx);
    ushort4 oh, ol;
    oh.x = f2bf(v.x); ol.x = f2bf(v.x - bf2f(oh.x));
    oh.y = f2bf(v.y); ol.y = f2bf(v.y - bf2f(oh.y));
    oh.z = f2bf(v.z); ol.z = f2bf(v.z - bf2f(oh.z));
    oh.w = f2bf(v.w); ol.w = f2bf(v.w - bf2f(oh.w));
    *(ushort4*)(hi + idx) = oh;
    *(ushort4*)(lo + idx) = ol;
}

// ------------------- transpose + hi/lo split: W[k][n] -> Wt_hi/lo[n][k] ----
__global__ __launch_bounds__(256)
void convT2_k(const float* __restrict__ W,
              ushort* __restrict__ Wth, ushort* __restrict__ Wtl)
{
    __shared__ float tile[32][33];
    const int k0 = blockIdx.x * 32, n0 = blockIdx.y * 32;
    const int tx = threadIdx.x & 31, ty = threadIdx.x >> 5;   // ty 0..7
    #pragma unroll
    for (int i = 0; i < 4; ++i)
        tile[ty + i*8][tx] = W[(size_t)(k0 + ty + i*8) * 1024 + n0 + tx];
    __syncthreads();
    #pragma unroll
    for (int i = 0; i < 4; ++i) {
        const float v = tile[tx][ty + i*8];
        const ushort h = f2bf(v);
        Wth[(size_t)(n0 + ty + i*8) * 1024 + k0 + tx] = h;
        Wtl[(size_t)(n0 + ty + i*8) * 1024 + k0 + tx] = f2bf(v - bf2f(h));
    }
}

// ------------------- transpose + convert (single bf16): W[k][n]->Wt[n][k] --
__global__ __launch_bounds__(256)
void convT_k(const float* __restrict__ W, ushort* __restrict__ Wt)
{
    __shared__ float tile[32][33];
    const int k0 = blockIdx.x * 32, n0 = blockIdx.y * 32;
    const int tx = threadIdx.x & 31, ty = threadIdx.x >> 5;
    #pragma unroll
    for (int i = 0; i < 4; ++i)
        tile[ty + i*8][tx] = W[(size_t)(k0 + ty + i*8) * 1024 + n0 + tx];
    __syncthreads();
    #pragma unroll
    for (int i = 0; i < 4; ++i)
        Wt[(size_t)(n0 + ty + i*8) * 1024 + k0 + tx] = f2bf(tile[tx][ty + i*8]);
}

// ----------------------------------- split-bf16 MFMA GEMM (z, fp32-class) --
// C = tanh(A @ B + bias), A=[8192x1024] via (Ah+Al), Bt=B^T via (Bh+Bl).
// acc += Ah·Bh + Ah·Bl + Al·Bh   (missing Al·Bl ~ 2^-18 rel — below fp32 noise)
__global__ __launch_bounds__(256)
void gemm_mfma_hp(const ushort* __restrict__ Ah, const ushort* __restrict__ Al,
                  const ushort* __restrict__ Bh, const ushort* __restrict__ Bl,
                  float* __restrict__ C, const float* __restrict__ bias)
{
    __shared__ ushort AsmH[128*32], AsmL[128*32];
    __shared__ ushort BsmH[128*32], BsmL[128*32];
    const int t = threadIdx.x, lane = t & 63, w = t >> 6;
    const int wr = w >> 1, wc = w & 1;
    const int row0 = blockIdx.x * 128, col0 = blockIdx.y * 128;

    const int lr = lane >> 2;
    const int lc = (lane & 3) ^ (lr & 3);
    const size_t aoff0 = (size_t)(row0 +      w*16 + lr) * 1024 + lc*8;
    const size_t aoff1 = (size_t)(row0 + 64 + w*16 + lr) * 1024 + lc*8;
    const size_t boff0 = (size_t)(col0 +      w*16 + lr) * 1024 + lc*8;
    const size_t boff1 = (size_t)(col0 + 64 + w*16 + lr) * 1024 + lc*8;
    ushort* lds0 = (ushort*)nullptr;
    (void)lds0;
    ushort* AH0 = AsmH + (     w*16) * 32;  ushort* AH1 = AsmH + (64 + w*16) * 32;
    ushort* AL0 = AsmL + (     w*16) * 32;  ushort* AL1 = AsmL + (64 + w*16) * 32;
    ushort* BH0 = BsmH + (     w*16) * 32;  ushort* BH1 = BsmH + (64 + w*16) * 32;
    ushort* BL0 = BsmL + (     w*16) * 32;  ushort* BL1 = BsmL + (64 + w*16) * 32;

    f32x4 acc[4][4];
    #pragma unroll
    for (int i = 0; i < 4; ++i)
        #pragma unroll
        for (int j = 0; j < 4; ++j) acc[i][j] = (f32x4){0.f,0.f,0.f,0.f};

    const int quad = lane >> 4;
    const int fr   = lane & 15;
    const int fchk = (quad ^ (lane & 3)) * 8;

    for (int k0 = 0; k0 < 1024; k0 += 32) {
        __syncthreads();
        gl_lds16(Ah + aoff0 + k0, AH0);
        gl_lds16(Ah + aoff1 + k0, AH1);
        gl_lds16(Bh + boff0 + k0, BH0);
        gl_lds16(Bh + boff1 + k0, BH1);
        gl_lds16(Al + aoff0 + k0, AL0);
        gl_lds16(Al + aoff1 + k0, AL1);
        gl_lds16(Bl + boff0 + k0, BL0);
        gl_lds16(Bl + boff1 + k0, BL1);
        __syncthreads();

        bf16x8 afh[4], afl[4], bfh[4], bfl[4];
        #pragma unroll
        for (int i = 0; i < 4; ++i) {
            const int ra = (wr*64 + i*16 + fr) * 32 + fchk;
            afh[i] = *(const bf16x8*)(AsmH + ra);
            afl[i] = *(const bf16x8*)(AsmL + ra);
            const int rb = (wc*64 + i*16 + fr) * 32 + fchk;
            bfh[i] = *(const bf16x8*)(BsmH + rb);
            bfl[i] = *(const bf16x8*)(BsmL + rb);
        }
        #pragma unroll
        for (int i = 0; i < 4; ++i)
            #pragma unroll
            for (int j = 0; j < 4; ++j) {
                acc[i][j] = __builtin_amdgcn_mfma_f32_16x16x32_bf16(
                    afh[i], bfl[j], acc[i][j], 0, 0, 0);
                acc[i][j] = __builtin_amdgcn_mfma_f32_16x16x32_bf16(
                    afl[i], bfh[j], acc[i][j], 0, 0, 0);
                acc[i][j] = __builtin_amdgcn_mfma_f32_16x16x32_bf16(
                    afh[i], bfh[j], acc[i][j], 0, 0, 0);
            }
    }

    float colv[4];
    #pragma unroll
    for (int tj = 0; tj < 4; ++tj)
        colv[tj] = bias[col0 + wc*64 + tj*16 + fr];
    #pragma unroll
    for (int ti = 0; ti < 4; ++ti)
        #pragma unroll
        for (int i = 0; i < 4; ++i) {
            const int row = row0 + wr*64 + ti*16 + quad*4 + i;
            #pragma unroll
            for (int tj = 0; tj < 4; ++tj) {
                const int col = col0 + wc*64 + tj*16 + fr;
                C[(size_t)row*1024 + col] = tanhf(acc[ti][tj][i] + colv[tj]);
            }
        }
}

// --------------------------------------------------- plain bf16 MFMA GEMM --
// EPI 2: v + sum_h scores[row,h]*b2[h,col]   (weighted; direct-to-output path)
__global__ __launch_bounds__(256)
void gemm_mfma(const ushort* __restrict__ A, const ushort* __restrict__ Bt,
               float* __restrict__ C,
               const float* __restrict__ scores, const float* __restrict__ b2)
{
    __shared__ ushort Asm[128*32];
    __shared__ ushort Bsm[128*32];
    const int t = threadIdx.x, lane = t & 63, w = t >> 6;
    const int wr = w >> 1, wc = w & 1;
    const int row0 = blockIdx.x * 128, col0 = blockIdx.y * 128;

    const int lr = lane >> 2;
    const int lc = (lane & 3) ^ (lr & 3);
    const ushort* Ag0 = A  + (size_t)(row0 +      w*16 + lr) * 1024 + lc*8;
    const ushort* Ag1 = A  + (size_t)(row0 + 64 + w*16 + lr) * 1024 + lc*8;
    const ushort* Bg0 = Bt + (size_t)(col0 +      w*16 + lr) * 1024 + lc*8;
    const ushort* Bg1 = Bt + (size_t)(col0 + 64 + w*16 + lr) * 1024 + lc*8;
    ushort* Al0 = Asm + (     w*16) * 32;
    ushort* Al1 = Asm + (64 + w*16) * 32;
    ushort* Bl0 = Bsm + (     w*16) * 32;
    ushort* Bl1 = Bsm + (64 + w*16) * 32;

    f32x4 acc[4][4];
    #pragma unroll
    for (int i = 0; i < 4; ++i)
        #pragma unroll
        for (int j = 0; j < 4; ++j) acc[i][j] = (f32x4){0.f,0.f,0.f,0.f};

    const int quad = lane >> 4;
    const int fr   = lane & 15;
    const int fchk = (quad ^ (lane & 3)) * 8;

    for (int k0 = 0; k0 < 1024; k0 += 32) {
        __syncthreads();
        gl_lds16(Ag0 + k0, Al0);
        gl_lds16(Ag1 + k0, Al1);
        gl_lds16(Bg0 + k0, Bl0);
        gl_lds16(Bg1 + k0, Bl1);
        __syncthreads();

        bf16x8 af[4], bf[4];
        #pragma unroll
        for (int i = 0; i < 4; ++i) {
            af[i] = *(const bf16x8*)(Asm + (wr*64 + i*16 + fr)*32 + fchk);
            bf[i] = *(const bf16x8*)(Bsm + (wc*64 + i*16 + fr)*32 + fchk);
        }
        #pragma unroll
        for (int i = 0; i < 4; ++i)
            #pragma unroll
            for (int j = 0; j < 4; ++j)
                acc[i][j] = __builtin_amdgcn_mfma_f32_16x16x32_bf16(
                    af[i], bf[j], acc[i][j], 0, 0, 0);
    }

    float b2v[4][HH];
    #pragma unroll
    for (int tj = 0; tj < 4; ++tj) {
        const int col = col0 + wc*64 + tj*16 + fr;
        #pragma unroll
        for (int h = 0; h < HH; ++h) b2v[tj][h] = b2[(size_t)h*EE + col];
    }
    #pragma unroll
    for (int ti = 0; ti < 4; ++ti)
        #pragma unroll
        for (int i = 0; i < 4; ++i) {
            const int row = row0 + wr*64 + ti*16 + quad*4 + i;
            float sc[HH];
            #pragma unroll
            for (int h = 0; h < HH; ++h) sc[h] = scores[row*HH + h];
            #pragma unroll
            for (int tj = 0; tj < 4; ++tj) {
                const int col = col0 + wc*64 + tj*16 + fr;
                float bb = 0.f;
                #pragma unroll
                for (int h = 0; h < HH; ++h) bb = fmaf(sc[h], b2v[tj][h], bb);
                C[(size_t)row*1024 + col] = acc[ti][tj][i] + bb;
            }
        }
}

// ------------------------------------------- fp32 GEMM (h1, K=128/head) ----
__global__ __launch_bounds__(256)
void gemm_k(const float* __restrict__ A, int lda, int aOff,
            const float* __restrict__ Bm, int ldb, int bOff,
            float* __restrict__ C, int ldc, int cOff,
            int K,
            const float* __restrict__ bias, int biasOff)
{
    const int zb = blockIdx.z;
    const float* Ab = A  + (size_t)zb * aOff;
    const float* Bb = Bm + (size_t)zb * bOff;
    float*       Cb = C  + (size_t)zb * cOff;
    const float* biasb = bias + (size_t)zb * biasOff;
    const int row0 = blockIdx.x * 128;
    const int col0 = blockIdx.y * 128;

    __shared__ float Asm[8][128];
    __shared__ float Bsm[8][128];

    const int t  = threadIdx.x;
    const int tx = t & 15, ty = t >> 4;
    const int am = t >> 1, ak = (t & 1) * 4;
    const int bk = t >> 5, bn = (t & 31) * 4;

    float acc[8][8];
    #pragma unroll
    for (int i = 0; i < 8; ++i)
        #pragma unroll
        for (int j = 0; j < 8; ++j) acc[i][j] = 0.f;

    for (int k0 = 0; k0 < K; k0 += 8) {
        const float4 av = *(const float4*)(Ab + (size_t)(row0 + am) * lda + k0 + ak);
        const float4 bv = *(const float4*)(Bb + (size_t)(k0 + bk) * ldb + col0 + bn);
        __syncthreads();
        Asm[ak+0][am] = av.x; Asm[ak+1][am] = av.y;
        Asm[ak+2][am] = av.z; Asm[ak+3][am] = av.w;
        *(float4*)&Bsm[bk][bn] = bv;
        __syncthreads();
        #pragma unroll
        for (int kk = 0; kk < 8; ++kk) {
            float a[8], b[8];
            *(float4*)&a[0] = *(const float4*)&Asm[kk][ty*8];
            *(float4*)&a[4] = *(const float4*)&Asm[kk][ty*8+4];
            *(float4*)&b[0] = *(const float4*)&Bsm[kk][tx*8];
            *(float4*)&b[4] = *(const float4*)&Bsm[kk][tx*8+4];
            #pragma unroll
            for (int i = 0; i < 8; ++i)
                #pragma unroll
                for (int j = 0; j < 8; ++j)
                    acc[i][j] = fmaf(a[i], b[j], acc[i][j]);
        }
    }

    #pragma unroll
    for (int i = 0; i < 8; ++i) {
        const int r = row0 + ty*8 + i;
        float outv[8];
        #pragma unroll
        for (int j = 0; j < 8; ++j) {
            const int cidx = col0 + tx*8 + j;
            float v = acc[i][j] + biasb[cidx];
            v = 0.5f * v * (1.f + erff(v * 0.70710678118654752f));  // exact gelu
            outv[j] = v;
        }
        *(float4*)(Cb + (size_t)r*ldc + col0 + tx*8)     = *(float4*)&outv[0];
        *(float4*)(Cb + (size_t)r*ldc + col0 + tx*8 + 4) = *(float4*)&outv[4];
    }
}

// ------------------------------------------------- DPP wave reduction ------
__device__ __forceinline__ float dpp_add(float x, const int ctrl) {
    int y;
    switch (ctrl) {
        case 0x111: y = __builtin_amdgcn_update_dpp(0, __float_as_int(x), 0x111, 0xf, 0xf, true); break;
        case 0x112: y = __builtin_amdgcn_update_dpp(0, __float_as_int(x), 0x112, 0xf, 0xf, true); break;
        case 0x114: y = __builtin_amdgcn_update_dpp(0, __float_as_int(x), 0x114, 0xf, 0xf, true); break;
        case 0x118: y = __builtin_amdgcn_update_dpp(0, __float_as_int(x), 0x118, 0xf, 0xf, true); break;
        case 0x142: y = __builtin_amdgcn_update_dpp(0, __float_as_int(x), 0x142, 0xf, 0xf, true); break;
        default:    y = __builtin_amdgcn_update_dpp(0, __float_as_int(x), 0x143, 0xf, 0xf, true); break;
    }
    return x + __int_as_float(y);
}

__device__ __forceinline__ float wave_sum64(float x) {
    x = dpp_add(x, 0x111);
    x = dpp_add(x, 0x112);
    x = dpp_add(x, 0x114);
    x = dpp_add(x, 0x118);
    x = dpp_add(x, 0x142);
    x = dpp_add(x, 0x143);
    return __int_as_float(__builtin_amdgcn_readlane(__float_as_int(x), 63));
}

// ---------------------------------------------------------------- scan -----
__global__ __launch_bounds__(64)
void scan_k(const float* __restrict__ z,
            const float* __restrict__ uh_d, const float* __restrict__ uz_d,
            const float* __restrict__ b_u,
            const float* __restrict__ lns_g, const float* __restrict__ lns_b,
            float* __restrict__ states)
{
    const int bh = blockIdx.x;
    const int b = bh >> 3, h = bh & 7;
    const int lane = threadIdx.x;
    const int d0 = lane, d1 = lane + 64;

    const float uhn0 = -uh_d[h*DD + d0] * LOG2E, uhn1 = -uh_d[h*DD + d1] * LOG2E;
    const float uzn0 = -uz_d[h*DD + d0] * LOG2E, uzn1 = -uz_d[h*DD + d1] * LOG2E;
    const float bun0 = -b_u [h*DD + d0] * LOG2E, bun1 = -b_u [h*DD + d1] * LOG2E;
    const float g0  = lns_g[d0], g1 = lns_g[d1];
    const float be0 = lns_b[d0], be1 = lns_b[d1];

    const float* zp = z      + ((size_t)b * SS * HH + h) * DD;
    float*       sp = states + ((size_t)b * SS * HH + h) * DD;

    float hp0 = 0.f, hp1 = 0.f;
    const int CH = 8;
    float zc0[CH], zc1[CH], pr0[CH], pr1[CH];
    #pragma unroll
    for (int i = 0; i < CH; ++i) {
        zc0[i] = zp[(size_t)i*HD + d0];
        zc1[i] = zp[(size_t)i*HD + d1];
    }
    #pragma unroll
    for (int i = 0; i < CH; ++i) {
        pr0[i] = fmaf(zc0[i], uzn0, bun0);
        pr1[i] = fmaf(zc1[i], uzn1, bun1);
    }

    for (int s0 = 0; s0 < SS; s0 += CH) {
        float zn0[CH], zn1[CH];
        if (s0 + CH < SS) {
            #pragma unroll
            for (int i = 0; i < CH; ++i) {
                zn0[i] = zp[(size_t)(s0+CH+i)*HD + d0];
                zn1[i] = zp[(size_t)(s0+CH+i)*HD + d1];
            }
        } else {
            #pragma unroll
            for (int i = 0; i < CH; ++i) { zn0[i] = 0.f; zn1[i] = 0.f; }
        }
        #pragma unroll
        for (int i = 0; i < CH; ++i) {
            const float z0 = zc0[i], z1 = zc1[i];
            const float e0 = __builtin_amdgcn_exp2f(fmaf(hp0, uhn0, pr0[i]));
            const float e1 = __builtin_amdgcn_exp2f(fmaf(hp1, uhn1, pr1[i]));
            const float d0v = hp0 - z0;
            const float d1v = hp1 - z1;
            const float u0 = __builtin_amdgcn_rcpf(1.f + e0);
            const float u1 = __builtin_amdgcn_rcpf(1.f + e1);
            const float hn0 = fmaf(u0, d0v, z0);
            const float hn1 = fmaf(u1, d1v, z1);
            const float s1 = wave_sum64(hn0 + hn1);
            const float s2 = wave_sum64(fmaf(hn0, hn0, hn1*hn1));
            const float m   = s1 * (1.f/128.f);
            const float var = fmaf(s2, 1.f/128.f, -m*m);
            const float r   = __builtin_amdgcn_rsqf(var + LNEPS);
            const float rg0 = r * g0, rg1 = r * g1;
            hp0 = fmaf(hn0 - m, rg0, be0);
            hp1 = fmaf(hn1 - m, rg1, be1);
            sp[(size_t)(s0+i)*HD + d0] = hp0;
            sp[(size_t)(s0+i)*HD + d1] = hp1;
        }
        #pragma unroll
        for (int i = 0; i < CH; ++i) {
            zc0[i] = zn0[i]; zc1[i] = zn1[i];
            pr0[i] = fmaf(zn0[i], uzn0, bun0);
            pr1[i] = fmaf(zn1[i], uzn1, bun1);
        }
    }
}

// ------------------------------------------------- per-head diag+LN --------
__global__ __launch_bounds__(256)
void headln_k(const float* __restrict__ states, const float* __restrict__ os_d,
              const float* __restrict__ ffg, const float* __restrict__ ffb,
              float* __restrict__ hln)
{
    const int gid  = blockIdx.x * 256 + threadIdx.x;
    const int row  = gid >> 6;
    const int lane = gid & 63;
    const int h = row & 7;
    const float* xp = states + (size_t)row * DD;
    const float x0 = xp[lane]      * os_d[h*DD + lane];
    const float x1 = xp[lane + 64] * os_d[h*DD + lane + 64];
    float s1 = x0 + x1;
    float s2 = fmaf(x0, x0, x1*x1);
    #pragma unroll
    for (int off = 32; off > 0; off >>= 1) {
        s1 += __shfl_xor(s1, off, 64);
        s2 += __shfl_xor(s2, off, 64);
    }
    const float m   = s1 * (1.f/128.f);
    const float var = fmaf(s2, 1.f/128.f, -m*m);
    const float r   = rsqrtf(var + LNEPS);
    float* op = hln + (size_t)row * DD;
    op[lane]      = fmaf((x0 - m)*r, ffg[h*DD + lane],      ffb[h*DD + lane]);
    op[lane + 64] = fmaf((x1 - m)*r, ffg[h*DD + lane + 64], ffb[h*DD + lane + 64]);
}

// ---------------------------------------------------------------- logits ---
__global__ __launch_bounds__(256)
void logits_k(const float* __restrict__ h1, const float* __restrict__ q,
              const float* __restrict__ c, float* __restrict__ logits)
{
    const int gid  = blockIdx.x * 256 + threadIdx.x;
    const int row  = gid >> 6;
    const int lane = gid & 63;
    const int h = row & 7;
    const float* xp = h1 + (size_t)row * DD;
    float p = fmaf(xp[lane], q[h*DD + lane], xp[lane+64] * q[h*DD + lane + 64]);
    #pragma unroll
    for (int off = 32; off > 0; off >>= 1) p += __shfl_xor(p, off, 64);
    if (lane == 0) logits[row] = p + c[h];
}

// ------------------------------- softmax + scale h1 -> g (bf16) ------------
__global__ __launch_bounds__(256)
void softscale_k(const float* __restrict__ h1, const float* __restrict__ logits,
                 ushort* __restrict__ gb, float* __restrict__ scores)
{
    const int gid = blockIdx.x * 256 + threadIdx.x;
    const size_t idx = (size_t)gid * 4;
    const int bs = (int)(idx >> 10);
    const int h  = (int)((idx >> 7) & 7);
    float l[8];
    float mx = -1e30f;
    #pragma unroll
    for (int i = 0; i < 8; ++i) { l[i] = logits[bs*8 + i]; mx = fmaxf(mx, l[i]); }
    float den = 0.f;
    #pragma unroll
    for (int i = 0; i < 8; ++i) den += __expf(l[i] - mx);
    const float sc = __expf(l[h] - mx) / den;
    float4 v = *(const float4*)(h1 + idx);
    ushort4 o;
    o.x = f2bf(v.x * sc); o.y = f2bf(v.y * sc);
    o.z = f2bf(v.z * sc); o.w = f2bf(v.w * sc);
    *(ushort4*)(gb + idx) = o;
    if ((idx & 127) == 0) scores[bs*8 + h] = sc;
}

// ---------------------------------------------------------------- final LN -
__global__ __launch_bounds__(256)
void finalln_k(const float* __restrict__ w, const float* __restrict__ g,
               const float* __restrict__ b, float* __restrict__ out)
{
    const int row = blockIdx.x;
    const int t = threadIdx.x;
    const float* xp = w + (size_t)row * EE;
    const float4 v = *(const float4*)(xp + t*4);
    float s1 = v.x + v.y + v.z + v.w;
    float s2 = v.x*v.x + v.y*v.y + v.z*v.z + v.w*v.w;
    #pragma unroll
    for (int off = 32; off > 0; off >>= 1) {
        s1 += __shfl_xor(s1, off, 64);
        s2 += __shfl_xor(s2, off, 64);
    }
    __shared__ float r1[4], r2[4];
    if ((t & 63) == 0) { r1[t>>6] = s1; r2[t>>6] = s2; }
    __syncthreads();
    s1 = r1[0] + r1[1] + r1[2] + r1[3];
    s2 = r2[0] + r2[1] + r2[2] + r2[3];
    const float m   = s1 * (1.f/1024.f);
    const float var = fmaf(s2, 1.f/1024.f, -m*m);
    const float r   = rsqrtf(var + LNEPS);
    const float4 gv = *(const float4*)(g + t*4);
    const float4 bv = *(const float4*)(b + t*4);
    float4 o;
    o.x = fmaf((v.x - m)*r, gv.x, bv.x);
    o.y = fmaf((v.y - m)*r, gv.y, bv.y);
    o.z = fmaf((v.z - m)*r, gv.z, bv.z);
    o.w = fmaf((v.w - m)*r, gv.w, bv.w);
    *(float4*)(out + (size_t)row*EE + t*4) = o;
}

// ---------------------------------------------------------------------------
extern "C" void kernel_launch(void* const* d_in, const int* in_sizes, int n_in,
                              void* d_out, int out_size, void* d_ws, size_t ws_size,
                              hipStream_t stream)
{
    const float* x       = (const float*)d_in[0];
    const float* W_ez    = (const float*)d_in[1];
    const float* b_ez    = (const float*)d_in[2];
    const float* U_h     = (const float*)d_in[3];
    const float* U_z     = (const float*)d_in[4];
    const float* b_u     = (const float*)d_in[5];
    const float* outsh   = (const float*)d_in[6];
    const float* lns_g   = (const float*)d_in[7];
    const float* lns_b   = (const float*)d_in[8];
    const float* ff_ln_g = (const float*)d_in[9];
    const float* ff_ln_b = (const float*)d_in[10];
    const float* ff_W1   = (const float*)d_in[11];
    const float* ff_b1   = (const float*)d_in[12];
    const float* ff_W2   = (const float*)d_in[13];
    const float* ff_b2   = (const float*)d_in[14];
    const float* w_att   = (const float*)d_in[15];
    const float* b_att   = (const float*)d_in[16];
    const float* lno_g   = (const float*)d_in[17];
    const float* lno_b   = (const float*)d_in[18];
    float* out = (float*)d_out;

    float* ws = (float*)d_ws;
    const size_t NBIG = (size_t)BSR * HD;          // 8M floats
    float* bufA = ws;                              // z -> h1
    float* bufB = ws + NBIG;                       // xb_hi/lo -> states -> gb
    float* bufC = ws + 2*NBIG;                     // WezT hi/lo -> hln -> weighted
    float* ext  = ws + 3*NBIG;
    ushort* W2t   = (ushort*)ext;                  // 1M bf16 (512K floats)
    float* logits = ext + 512*1024;                // 64K
    float* scores = logits + BSR*HH;               // 64K
    float* qv     = scores + BSR*HH;               // 1024
    float* cv     = qv + HD;                       // 8
    float* uh_d   = cv + 8;
    float* uz_d   = uh_d + HD;
    float* os_d   = uz_d + HD;
    // aliases (lifetime-disjoint):
    ushort* xb_hi = (ushort*)bufB;                 // 8M ushorts
    ushort* xb_lo = (ushort*)bufB + NBIG;          // 8M ushorts (2nd half of bufB)
    ushort* gb    = (ushort*)bufB;                 // after states die
    ushort* WezT_hi = (ushort*)bufC;               // 1M ushorts
    ushort* WezT_lo = (ushort*)bufC + 1024*1024;   // 1M ushorts (die before hln)

    // 0: independent prep — split conversions, transposes, diagonals/q/c
    convx2_k<<<(BSR*EE/4)/256, 256, 0, stream>>>(x, xb_hi, xb_lo);
    convT2_k<<<dim3(32, 32), 256, 0, stream>>>(W_ez, WezT_hi, WezT_lo);
    convT_k<<<dim3(32, 32), 256, 0, stream>>>(ff_W2, W2t);
    prep_k<<<258, 256, 0, stream>>>(ff_W2, w_att, ff_b2, b_att,
                                    U_h, U_z, outsh, qv, cv, uh_d, uz_d, os_d);
    // 1: z = tanh(x @ W_ez + b_ez)   [split-bf16 MFMA, fp32-class accuracy]
    gemm_mfma_hp<<<dim3(64, 8), 256, 0, stream>>>(
        xb_hi, xb_lo, WezT_hi, WezT_lo, bufA, b_ez);
    // 2: sequential scan -> states
    scan_k<<<BB*HH, 64, 0, stream>>>(bufA, uh_d, uz_d, b_u, lns_g, lns_b, bufB);
    // 3: diag-scale + per-head LN -> hln
    headln_k<<<(BSR*HH*64)/256, 256, 0, stream>>>(bufB, os_d, ff_ln_g, ff_ln_b, bufC);
    // 4: h1 = gelu(hln @ W1[h] + b1[h])  (fp32, per-head)
    gemm_k<<<dim3(64, 1, 8), 256, 0, stream>>>(
        bufC, HD, DD, ff_W1, DD, DD*DD, bufA, HD, DD, DD, ff_b1, DD);
    // 5: logits = h1 . q[h] + c[h]
    logits_k<<<(BSR*HH*64)/256, 256, 0, stream>>>(bufA, qv, cv, logits);
    // 6: softmax over heads, gb = bf16(score * h1), stash scores
    softscale_k<<<(BSR*HD/4)/256, 256, 0, stream>>>(bufA, logits, gb, scores);
    // 7: weighted = g @ W2v + sum_h score_h*b2[h,:]   [bf16 MFMA]
    gemm_mfma<<<dim3(64, 8), 256, 0, stream>>>(gb, W2t, bufC, scores, ff_b2);
    // 8: final LayerNorm over E -> out
    finalln_k<<<BSR, 256, 0, stream>>>(bufC, lno_g, lno_b, out);
}